// Round 9
// baseline (251.474 us; speedup 1.0000x reference)
//
#include <hip/hip_runtime.h>

// Depthwise separable 4x4 FIR blur (StyleGAN2 upfirdn2d, up=down=1, pad=(2,2)).
// x: [B,C,256,256] f32, kernel: [4,4] f32 separable, out: [B,C,257,257] f32.
//
// out[q] = H[q+1] + v1*H[q] + v2*H[q-1] + v3*H[q-2],  H[r][c] = sum_j w[j]*x[r][c+1-j]
//
// R9: GLOBAL_LOAD_LDS PATH. R2-R8 plateau at ~235-262us (3.7 TB/s) across
// every per-wave/grid structure, all using VGPR-return loads. Hypothesis: the
// per-CU outstanding-miss capacity of the vector-load path caps read
// throughput (~4KB in flight x ~250ns = ~16 GB/s/CU = observed). This kernel
// switches the input stream to the direct-to-LDS DMA path:
//   wave = one 64-row strip; private 8-slot x 1KB LDS ring; rows staged by
//   width-16 global_load_lds with 1-iteration lead; counted vmcnt(8) waits
//   (correct for any store count >=4: leaves this iter's 4 stages in flight,
//   drains last iter's). Halo columns read straight from LDS (no shuffles).
// 32KB LDS/block -> 5 blocks/CU = 20 waves/CU.

#define IW 256
#define IH 256
#define OW 257
#define OH 257
#define NSLOT 8

typedef float f4u __attribute__((vector_size(16), aligned(4)));

__device__ __forceinline__ float sbc(float v) {   // wave-uniform -> SGPR
    return __uint_as_float(__builtin_amdgcn_readfirstlane(__float_as_uint(v)));
}

__device__ __forceinline__ void gld16(const float* g, float* l) {
    __builtin_amdgcn_global_load_lds(
        (const __attribute__((address_space(1))) void*)g,
        (__attribute__((address_space(3))) void*)l, 16, 0, 0);
}

#define WAIT_VM(n)   asm volatile("s_waitcnt vmcnt(" #n ")" ::: "memory")
#define WAIT_LGKM0() asm volatile("s_waitcnt lgkmcnt(0)" ::: "memory")

__global__ __launch_bounds__(256) void blur_fir_kernel(
    const float* __restrict__ x,
    const float* __restrict__ k2d,
    float* __restrict__ out)
{
    __shared__ float L[4][NSLOT * 256];            // 32 KB: 4 waves x 8 row-slots

    const int lane  = threadIdx.x & 63;
    const int wv    = threadIdx.x >> 6;            // wave = strip 0..3
    const int plane = blockIdx.x;
    const int r0    = wv << 6;

    const float w0 = sbc(k2d[0]);
    const float w1 = sbc(k2d[1]);
    const float w2 = sbc(k2d[2]);
    const float w3 = sbc(k2d[3]);
    const float inv = 1.0f / w0;
    const float v1 = sbc(k2d[4]  * inv);
    const float v2 = sbc(k2d[8]  * inv);
    const float v3 = sbc(k2d[12] * inv);

    const int   c0   = lane << 2;                  // 4 output cols per lane
    const float mL   = (lane > 0)  ? 1.0f : 0.0f;
    const float mR   = (lane < 63) ? 1.0f : 0.0f;
    const int   offL = (lane > 0)  ? c0 - 2 : 0;   // clamped, in [0,256)
    const int   offR = (lane < 63) ? c0 + 4 : 0;
    const bool  last = (lane == 63);

    const float* xp = x + ((size_t)plane << 16);
    float* Lw = L[wv];

    // Stage input row r (clamped; OOB masked at compute) into slot r&7.
    // One global_load_lds(16B): lane l supplies src bytes [16l,16l+16) and HW
    // writes LDS base+16l — exactly row-major layout. vmcnt-tracked, async.
    auto stage = [&](int r) {
        int rr = min(max(r, 0), IH - 1);
        gld16(xp + (rr << 8) + c0, Lw + ((r & (NSLOT - 1)) << 8));
    };
    // Horizontal filter of staged row r, read straight from LDS (halo free).
    auto hcombL = [&](int r, float4& h, float& h4) {
        const float* rowp = Lw + ((r & (NSLOT - 1)) << 8);
        float rm = (r >= 0 && r < IH) ? 1.0f : 0.0f;
        float2 Lv = *(const float2*)(rowp + offL);
        float4 Bv = *(const float4*)(rowp + c0);
        float  Rv = rowp[offR];
        float lx = Lv.x * mL, ly = Lv.y * mL, rv = Rv * mR;
        h.x = w0 * Bv.y + w1 * Bv.x + w2 * ly   + w3 * lx;
        h.y = w0 * Bv.z + w1 * Bv.y + w2 * Bv.x + w3 * ly;
        h.z = w0 * Bv.w + w1 * Bv.z + w2 * Bv.y + w3 * Bv.x;
        h.w = w0 * rv   + w1 * Bv.w + w2 * Bv.z + w3 * Bv.y;
        h4  = w2 * Bv.w + w3 * Bv.z;               // out col 256 (lane 63 only)
        h.x *= rm; h.y *= rm; h.z *= rm; h.w *= rm; h4 *= rm;
    };
    auto vcomb = [&](float4 a, float4 b, float4 c, float4 d) -> float4 {
        float4 r;
        r.x = a.x + v1 * b.x + v2 * c.x + v3 * d.x;
        r.y = a.y + v1 * b.y + v2 * c.y + v3 * d.y;
        r.z = a.z + v1 * b.z + v2 * c.z + v3 * d.z;
        r.w = a.w + v1 * b.w + v2 * c.w + v3 * d.w;
        return r;
    };

    // Prologue: stage rows r0-2..r0+4 (7 ops), drain, compute carries.
    stage(r0 - 2); stage(r0 - 1); stage(r0);
    stage(r0 + 1); stage(r0 + 2); stage(r0 + 3); stage(r0 + 4);
    WAIT_VM(0);
    __builtin_amdgcn_sched_barrier(0);

    float4 C0, C1, C2; float sc0, sc1, sc2;
    hcombL(r0 - 2, C0, sc0);
    hcombL(r0 - 1, C1, sc1);
    hcombL(r0,     C2, sc2);
    WAIT_LGKM0();                                   // retire ds_reads before
    __builtin_amdgcn_sched_barrier(0);              // ring slots get overwritten

    float* op = out + (size_t)plane * (OW * OH) + (size_t)r0 * OW + c0;

    #pragma unroll 1
    for (int i = 0; i < 16; ++i) {
        const int a = r0 + (i << 2);                // out rows a..a+3
        // Stage next group's rows (consumed next iter): 1-iteration lead.
        stage(a + 5); stage(a + 6); stage(a + 7); stage(a + 8);
        // Drain last iter's stages (rows a+1..a+4); keep these 4 + any
        // younger in flight. Correct for any store count >= 4.
        WAIT_VM(8);
        __builtin_amdgcn_sched_barrier(0);

        float4 F0, F1, F2, F3; float sf0, sf1, sf2, sf3;
        hcombL(a + 1, F0, sf0);
        hcombL(a + 2, F1, sf1);
        hcombL(a + 3, F2, sf2);
        hcombL(a + 4, F3, sf3);

        float4 R0 = vcomb(F0, C2, C1, C0);          // out row a
        float4 R1 = vcomb(F1, F0, C2, C1);
        float4 R2 = vcomb(F2, F1, F0, C2);
        float4 R3 = vcomb(F3, F2, F1, F0);
        *(f4u*)(op         ) = (f4u){R0.x, R0.y, R0.z, R0.w};
        *(f4u*)(op +     OW) = (f4u){R1.x, R1.y, R1.z, R1.w};
        *(f4u*)(op + 2 * OW) = (f4u){R2.x, R2.y, R2.z, R2.w};
        *(f4u*)(op + 3 * OW) = (f4u){R3.x, R3.y, R3.z, R3.w};
        if (last) {
            op[4]          = sf0 + v1 * sc2 + v2 * sc1 + v3 * sc0;
            op[OW + 4]     = sf1 + v1 * sf0 + v2 * sc2 + v3 * sc1;
            op[2 * OW + 4] = sf2 + v1 * sf1 + v2 * sf0 + v3 * sc2;
            op[3 * OW + 4] = sf3 + v1 * sf2 + v2 * sf1 + v3 * sf0;
        }
        op += 4 * OW;

        C0 = F1;  C1 = F2;  C2 = F3;
        sc0 = sf1; sc1 = sf2; sc2 = sf3;
    }

    if (wv == 3) {                                  // out row 256
        // H[256]=H[257]=0 -> v2*H[255] + v3*H[254] = v2*C1 + v3*C0
        float4 R;
        R.x = v2 * C1.x + v3 * C0.x;
        R.y = v2 * C1.y + v3 * C0.y;
        R.z = v2 * C1.z + v3 * C0.z;
        R.w = v2 * C1.w + v3 * C0.w;
        *(f4u*)op = (f4u){R.x, R.y, R.z, R.w};
        if (last) op[4] = v2 * sc1 + v3 * sc0;
    }
}

extern "C" void kernel_launch(void* const* d_in, const int* in_sizes, int n_in,
                              void* d_out, int out_size, void* d_ws, size_t ws_size,
                              hipStream_t stream) {
    const float* x   = (const float*)d_in[0];
    const float* k2d = (const float*)d_in[1];
    float* out = (float*)d_out;

    int nplanes = in_sizes[0] >> 16;                // B*C = 2048
    blur_fir_kernel<<<nplanes, 256, 0, stream>>>(x, k2d, out);
}